// Round 1
// baseline (932.551 us; speedup 1.0000x reference)
//
#include <hip/hip_runtime.h>
#include <math.h>

#define SPX 16384   // H*W = 128*128

// ---------------------------------------------------------------------------
// GEMM: C[z][m][n] = alpha * sum_k W[m][k] * X[z][k][n]
// BM=BN=64, BK=16, 256 threads, 4x4 microtile. M%64==0, N%64==0, K%16==0.
// ---------------------------------------------------------------------------
__global__ __launch_bounds__(256) void gemm1x1(
    const float* __restrict__ Wm, const float* __restrict__ X, float* __restrict__ C,
    int M, int N, int K, long sX, long sC, float alpha)
{
    __shared__ float As[16][68];   // A tile transposed: As[k][m], pad 68 (16B-aligned rows)
    __shared__ float Bs[16][64];   // B tile: Bs[k][n]
    const int tid = threadIdx.x;
    const int tx = tid & 15, ty = tid >> 4;
    const int m0 = blockIdx.y * 64;
    const int n0 = blockIdx.x * 64;
    const long xb = (long)blockIdx.z * sX;
    const long cb = (long)blockIdx.z * sC;
    const int ac = tid & 15, ar0 = tid >> 4;   // A load: col=ac, row=ar0+16*it
    const int bj = tid & 63, bc0 = tid >> 6;   // B load: col=bj, row=bc0+4*it

    float acc[4][4] = {};
    for (int k0 = 0; k0 < K; k0 += 16) {
        __syncthreads();
        #pragma unroll
        for (int it = 0; it < 4; ++it) {
            int r = ar0 + it * 16;
            As[ac][r] = Wm[(long)(m0 + r) * K + k0 + ac];
        }
        #pragma unroll
        for (int it = 0; it < 4; ++it) {
            int cr = bc0 + it * 4;
            Bs[cr][bj] = X[xb + (long)(k0 + cr) * N + n0 + bj];
        }
        __syncthreads();
        #pragma unroll
        for (int kk = 0; kk < 16; ++kk) {
            float av[4], bv[4];
            *(float4*)av = *(const float4*)&As[kk][ty * 4];
            *(float4*)bv = *(const float4*)&Bs[kk][tx * 4];
            #pragma unroll
            for (int i = 0; i < 4; ++i)
                #pragma unroll
                for (int j = 0; j < 4; ++j)
                    acc[i][j] = fmaf(av[i], bv[j], acc[i][j]);
        }
    }
    #pragma unroll
    for (int i = 0; i < 4; ++i) {
        float4 o;
        o.x = acc[i][0] * alpha; o.y = acc[i][1] * alpha;
        o.z = acc[i][2] * alpha; o.w = acc[i][3] * alpha;
        *(float4*)&C[cb + (long)(m0 + ty * 4 + i) * N + n0 + tx * 4] = o;
    }
}

// ---------------------------------------------------------------------------
// Depthwise 3x3, SAME (zero pad), H=W=128. One thread per output pixel.
// Y: [nchan][SPX] chunk, Wd: per-chunk weight base (chan-contiguous, 9 each).
// ---------------------------------------------------------------------------
__global__ __launch_bounds__(256) void dwconv3x3(
    const float* __restrict__ Y, const float* __restrict__ Wd, float* __restrict__ O)
{
    const int ci = blockIdx.y;
    const int p = blockIdx.x * 256 + threadIdx.x;
    const int y = p >> 7, x = p & 127;
    const float* __restrict__ src = Y + (long)ci * SPX;
    const float* wp = Wd + ci * 9;
    float s = 0.f;
    #pragma unroll
    for (int ky = 0; ky < 3; ++ky) {
        int yy = y + ky - 1;
        if ((unsigned)yy < 128u) {
            const float* row = src + yy * 128;
            #pragma unroll
            for (int kx = 0; kx < 3; ++kx) {
                int xx = x + kx - 1;
                if ((unsigned)xx < 128u)
                    s = fmaf(wp[ky * 3 + kx], row[xx], s);
            }
        }
    }
    O[(long)ci * SPX + p] = s;
}

// ---------------------------------------------------------------------------
// Gram + norms per (n,head): G[c][d] = sum_s q[c][s]*k[d][s];
// nq[c] = sum q^2, nk[d] = sum k^2.  Split-K over 32 chunks of 512, atomics.
// grid (32 chunks, 16 groups), 256 threads, each owns a 3x3 (c,d) tile.
// ---------------------------------------------------------------------------
__global__ __launch_bounds__(256) void gram48(
    const float* __restrict__ qkv, float* __restrict__ G,
    float* __restrict__ nq, float* __restrict__ nk)
{
    __shared__ float qs[48 * 132];   // [48][128] pad->132 (16B-aligned rows)
    __shared__ float ks[48 * 132];
    const int g = blockIdx.y;
    const int nb = g >> 3, h = g & 7;
    const long qb = ((long)nb * 1152 + h * 48) * SPX;
    const long kb = ((long)nb * 1152 + 384 + h * 48) * SPX;
    const int tid = threadIdx.x;
    const int cg = tid >> 4, dg = tid & 15;   // 16x16 tile grid, 3x3 each
    float acc[3][3] = {};
    float nacc = 0.f;
    const int nc = tid % 48, nwhich = tid / 48;  // norms: tid<96
    const int sch = blockIdx.x * 512;

    for (int sc = 0; sc < 4; ++sc) {
        const int sb = sch + sc * 128;
        __syncthreads();
        #pragma unroll
        for (int i = 0; i < 24; ++i) {
            int idx = tid + i * 256;           // 6144 elements
            int c = idx >> 7, s = idx & 127;
            qs[c * 132 + s] = qkv[qb + (long)c * SPX + sb + s];
            ks[c * 132 + s] = qkv[kb + (long)c * SPX + sb + s];
        }
        __syncthreads();
        const float4* q0 = (const float4*)&qs[(cg * 3 + 0) * 132];
        const float4* q1 = (const float4*)&qs[(cg * 3 + 1) * 132];
        const float4* q2 = (const float4*)&qs[(cg * 3 + 2) * 132];
        const float4* k0 = (const float4*)&ks[(dg * 3 + 0) * 132];
        const float4* k1 = (const float4*)&ks[(dg * 3 + 1) * 132];
        const float4* k2 = (const float4*)&ks[(dg * 3 + 2) * 132];
        #pragma unroll 8
        for (int s4 = 0; s4 < 32; ++s4) {
            float4 qv[3] = { q0[s4], q1[s4], q2[s4] };
            float4 kv[3] = { k0[s4], k1[s4], k2[s4] };
            #pragma unroll
            for (int i = 0; i < 3; ++i)
                #pragma unroll
                for (int j = 0; j < 3; ++j)
                    acc[i][j] += qv[i].x * kv[j].x + qv[i].y * kv[j].y
                               + qv[i].z * kv[j].z + qv[i].w * kv[j].w;
        }
        if (tid < 96) {
            const float4* nr4 = (const float4*)((nwhich ? ks : qs) + nc * 132);
            #pragma unroll 8
            for (int s4 = 0; s4 < 32; ++s4) {
                float4 v = nr4[s4];
                nacc += v.x * v.x + v.y * v.y + v.z * v.z + v.w * v.w;
            }
        }
    }
    #pragma unroll
    for (int i = 0; i < 3; ++i)
        #pragma unroll
        for (int j = 0; j < 3; ++j)
            atomicAdd(&G[g * 2304 + (cg * 3 + i) * 48 + (dg * 3 + j)], acc[i][j]);
    if (tid < 96) atomicAdd((nwhich ? nk : nq) + g * 48 + nc, nacc);
}

// ---------------------------------------------------------------------------
// A[c][d] = softmax_d( G[c][d] / (max(|q_c|,eps)*max(|k_d|,eps)) * temp4[h] )
// grid 16, block 64 (48 active rows; one thread per row c).
// ---------------------------------------------------------------------------
__global__ void attn_softmax48(const float* __restrict__ G, const float* __restrict__ nq,
                               const float* __restrict__ nk, const float* __restrict__ temp4,
                               float* __restrict__ A)
{
    const int g = blockIdx.x;
    const int c = threadIdx.x;
    if (c >= 48) return;
    const int h = g & 7;
    const float t = temp4[h];
    const float rq = 1.f / fmaxf(sqrtf(nq[g * 48 + c]), 1e-12f);
    float row[48];
    float mx = -1e30f;
    #pragma unroll
    for (int d = 0; d < 48; ++d) {
        float rk = 1.f / fmaxf(sqrtf(nk[g * 48 + d]), 1e-12f);
        float v = G[g * 2304 + c * 48 + d] * rq * rk * t;
        row[d] = v;
        mx = fmaxf(mx, v);
    }
    float sum = 0.f;
    #pragma unroll
    for (int d = 0; d < 48; ++d) { float e = expf(row[d] - mx); row[d] = e; sum += e; }
    const float inv = 1.f / sum;
    #pragma unroll
    for (int d = 0; d < 48; ++d) A[g * 2304 + c * 48 + d] = row[d] * inv;
}

// ---------------------------------------------------------------------------
// outc[(g*48+c)][s] = sum_d A[c][d] * v[d][s];  grid (64 s-tiles, 16 groups).
// ---------------------------------------------------------------------------
__global__ __launch_bounds__(256) void applyv48(
    const float* __restrict__ qkv, const float* __restrict__ A, float* __restrict__ outc)
{
    __shared__ float AT[48 * 52];    // AT[d][c], pad 52 (16B-aligned rows)
    __shared__ float vs[48 * 256];
    const int g = blockIdx.y, tid = threadIdx.x;
    const int nb = g >> 3, h = g & 7;
    const long vb = ((long)nb * 1152 + 768 + h * 48) * SPX;
    const int s0 = blockIdx.x * 256;
    #pragma unroll
    for (int i = 0; i < 9; ++i) {
        int idx = tid + i * 256;                 // 2304
        int c = idx / 48, d = idx % 48;
        AT[d * 52 + c] = A[g * 2304 + idx];
    }
    #pragma unroll 8
    for (int d = 0; d < 48; ++d)
        vs[d * 256 + tid] = qkv[vb + (long)d * SPX + s0 + tid];
    __syncthreads();
    const long ob = (long)g * 48 * SPX + s0 + tid;
    for (int cg = 0; cg < 12; ++cg) {
        float a0 = 0.f, a1 = 0.f, a2 = 0.f, a3 = 0.f;
        #pragma unroll
        for (int d = 0; d < 48; ++d) {
            float vd = vs[d * 256 + tid];
            float4 av = *(const float4*)&AT[d * 52 + cg * 4];
            a0 = fmaf(av.x, vd, a0);
            a1 = fmaf(av.y, vd, a1);
            a2 = fmaf(av.z, vd, a2);
            a3 = fmaf(av.w, vd, a3);
        }
        outc[ob + (long)(cg * 4 + 0) * SPX] = a0;
        outc[ob + (long)(cg * 4 + 1) * SPX] = a1;
        outc[ob + (long)(cg * 4 + 2) * SPX] = a2;
        outc[ob + (long)(cg * 4 + 3) * SPX] = a3;
    }
}

// ---------------------------------------------------------------------------
// Workspace layout (floats):
//   QKV  : [0, 37748736)                 2*1152*16384  (dwconv output, fp32)
//   OUTC : [37748736, 50331648)          2*384*16384   (aliases YCH; stage-disjoint)
//   YCH  : = OUTC (6291456 used)         conv1x1 chunk buffer
//   G    : [50331648, +36864)  NQ: +768  NK: +768  AAT: +36864
// peak ~201.6 MB
// ---------------------------------------------------------------------------
extern "C" void kernel_launch(void* const* d_in, const int* in_sizes, int n_in,
                              void* d_out, int out_size, void* d_ws, size_t ws_size,
                              hipStream_t stream)
{
    const float* x      = (const float*)d_in[0];
    const float* qkv_w  = (const float*)d_in[2];
    const float* dw_w   = (const float*)d_in[3];
    const float* proj_w = (const float*)d_in[4];
    const float* temp4  = (const float*)d_in[7];
    float* ws  = (float*)d_ws;
    float* out = (float*)d_out;

    float* QKV  = ws;
    float* OUTC = ws + 37748736L;
    float* YCH  = OUTC;                 // alias: dead before OUTC is written
    float* G    = ws + 50331648L;
    float* NQ   = G + 36864;
    float* NK   = NQ + 768;
    float* AAT  = NK + 768;

    // stage 1: qkv = dwconv3(conv1x1(x, qkv_w), dw_w), 6 chunks of 384 channels
    for (int chunk = 0; chunk < 6; ++chunk) {
        const int b = chunk / 3, part = chunk % 3;
        gemm1x1<<<dim3(256, 6, 1), 256, 0, stream>>>(
            qkv_w + (long)part * 384 * 384, x + (long)b * 384 * SPX, YCH,
            384, SPX, 384, 0L, 0L, 1.0f);
        dwconv3x3<<<dim3(64, 384), 256, 0, stream>>>(
            YCH, dw_w + (long)part * 384 * 9,
            QKV + ((long)b * 1152 + (long)part * 384) * SPX);
    }

    // stage 2: Gram + norms (split-K, atomics into zeroed buffers)
    hipMemsetAsync(G, 0, 38400 * sizeof(float), stream);
    gram48<<<dim3(32, 16), 256, 0, stream>>>(QKV, G, NQ, NK);

    // stage 3: cosine-sim softmax (48x48 per group)
    attn_softmax48<<<dim3(16), dim3(64), 0, stream>>>(G, NQ, NK, temp4, AAT);

    // stage 4: outc = A @ v
    applyv48<<<dim3(64, 16), 256, 0, stream>>>(QKV, AAT, OUTC);

    // stage 5: out = 2 * (proj_w @ outc)
    gemm1x1<<<dim3(256, 6, 2), 256, 0, stream>>>(
        proj_w, OUTC, out, 384, SPX, 384, (long)384 * SPX, (long)384 * SPX, 2.0f);
}

// Round 2
// 470.356 us; speedup vs baseline: 1.9827x; 1.9827x over previous
//
#include <hip/hip_runtime.h>
#include <math.h>

#define SPX 16384   // H*W = 128*128

typedef unsigned short ushort_t;
typedef __attribute__((ext_vector_type(8))) short bf16x8;
typedef __attribute__((ext_vector_type(4))) float f32x4;

static __device__ __forceinline__ ushort f2bf(float f) {
    union { float f; unsigned int u; } v; v.f = f;
    unsigned int r = v.u + 0x7FFFu + ((v.u >> 16) & 1u);   // RNE
    return (ushort)(r >> 16);
}
static __device__ __forceinline__ float bf2f(ushort u) {
    union { unsigned int u; float f; } v; v.u = ((unsigned int)u) << 16;
    return v.f;
}

// ---------------------------------------------------------------------------
// Transpose + convert: X[z][C][S] fp32 -> XT[z][S][C] bf16.  32x32 tiles.
// ---------------------------------------------------------------------------
__global__ __launch_bounds__(256) void transpose_cvt(
    const float* __restrict__ X, ushort* __restrict__ XT, int C, int S)
{
    __shared__ float t[32][33];
    const int s0 = blockIdx.x * 32, c0 = blockIdx.y * 32;
    const long zb = (long)blockIdx.z * C * S;
    const int tr = threadIdx.x >> 5, tc = threadIdx.x & 31;
    #pragma unroll
    for (int i = 0; i < 4; ++i) {
        int r = tr + i * 8;
        t[r][tc] = X[zb + (long)(c0 + r) * S + s0 + tc];
    }
    __syncthreads();
    #pragma unroll
    for (int i = 0; i < 4; ++i) {
        int r = tr + i * 8;     // s index within tile
        XT[zb + (long)(s0 + r) * C + c0 + tc] = f2bf(t[tc][r]);
    }
}

// ---------------------------------------------------------------------------
// Elementwise fp32 -> bf16 (weights)
// ---------------------------------------------------------------------------
__global__ __launch_bounds__(256) void cvt_bf16(
    const float* __restrict__ in, ushort* __restrict__ out, int n)
{
    int i = blockIdx.x * 256 + threadIdx.x;
    if (i < n) out[i] = f2bf(in[i]);
}

// ---------------------------------------------------------------------------
// bf16 MFMA GEMM (B-transposed input):
//   C[z][m][n] = alpha * sum_k A[m][k] * BT[z][n][k]
// 128x128 tile, BK=32, 256 threads (4 waves 2x2), 16x16x32 MFMA.
// M%128==0, N%128==0, K%32==0. OUT_BF16: 1 -> bf16 out, 0 -> fp32 out.
// ---------------------------------------------------------------------------
template<int OUT_BF16>
__global__ __launch_bounds__(256) void gemm_bt(
    const ushort* __restrict__ A, const ushort* __restrict__ BT,
    void* __restrict__ Cv, int M, int N, int K, long sB, long sC, float alpha)
{
    __shared__ ushort As[128 * 32];
    __shared__ ushort Bs[128 * 32];
    const int tid = threadIdx.x;
    const int w = tid >> 6;
    const int wr = w >> 1, wc = w & 1;
    const int lane = tid & 63;
    const int grp = lane >> 4, lr = lane & 15;
    const int m0 = blockIdx.y * 128, n0 = blockIdx.x * 128;
    const char* Ab = (const char*)A;
    const char* Bb = (const char*)(BT + (long)blockIdx.z * sB);

    f32x4 acc[4][4] = {};

    for (int k0 = 0; k0 < K; k0 += 32) {
        #pragma unroll
        for (int i = 0; i < 2; ++i) {
            const int o = (i * 256 + tid) * 16;   // byte offset within 8 KB tile
            const int row = o >> 6, kb = o & 63;  // 64 B per tile row (32 bf16)
            const char* ga = Ab + ((long)(m0 + row) * K + k0) * 2 + kb;
            const char* gb = Bb + ((long)(n0 + row) * K + k0) * 2 + kb;
            __builtin_amdgcn_global_load_lds(
                (const __attribute__((address_space(1))) unsigned int*)ga,
                (__attribute__((address_space(3))) unsigned int*)((char*)As + o), 16, 0, 0);
            __builtin_amdgcn_global_load_lds(
                (const __attribute__((address_space(1))) unsigned int*)gb,
                (__attribute__((address_space(3))) unsigned int*)((char*)Bs + o), 16, 0, 0);
        }
        __syncthreads();
        bf16x8 av[4], bv[4];
        #pragma unroll
        for (int mi = 0; mi < 4; ++mi)
            av[mi] = *(const bf16x8*)&As[(wr * 64 + mi * 16 + lr) * 32 + grp * 8];
        #pragma unroll
        for (int ni = 0; ni < 4; ++ni)
            bv[ni] = *(const bf16x8*)&Bs[(wc * 64 + ni * 16 + lr) * 32 + grp * 8];
        #pragma unroll
        for (int mi = 0; mi < 4; ++mi)
            #pragma unroll
            for (int ni = 0; ni < 4; ++ni)
                acc[mi][ni] = __builtin_amdgcn_mfma_f32_16x16x32_bf16(
                    av[mi], bv[ni], acc[mi][ni], 0, 0, 0);
        __syncthreads();
    }

    const long cb = (long)blockIdx.z * sC;
    #pragma unroll
    for (int mi = 0; mi < 4; ++mi) {
        #pragma unroll
        for (int ni = 0; ni < 4; ++ni) {
            const int r0 = m0 + wr * 64 + mi * 16 + grp * 4;
            const int c  = n0 + wc * 64 + ni * 16 + lr;
            #pragma unroll
            for (int j = 0; j < 4; ++j) {
                float vv = acc[mi][ni][j] * alpha;
                if (OUT_BF16) ((ushort*)Cv)[cb + (long)(r0 + j) * N + c] = f2bf(vv);
                else          ((float*)Cv)[cb + (long)(r0 + j) * N + c] = vv;
            }
        }
    }
}

// ---------------------------------------------------------------------------
// Depthwise 3x3, SAME (zero pad), H=W=128, bf16 in/out, fp32 weights.
// Y: [2304][SPX]; weight index = ci % 1152.
// ---------------------------------------------------------------------------
__global__ __launch_bounds__(256) void dwconv3x3(
    const ushort* __restrict__ Y, const float* __restrict__ Wd, ushort* __restrict__ O)
{
    const int ci = blockIdx.y;
    const int p = blockIdx.x * 256 + threadIdx.x;
    const int y = p >> 7, x = p & 127;
    const ushort* __restrict__ src = Y + (long)ci * SPX;
    const float* wp = Wd + (ci % 1152) * 9;
    float s = 0.f;
    #pragma unroll
    for (int ky = 0; ky < 3; ++ky) {
        int yy = y + ky - 1;
        if ((unsigned)yy < 128u) {
            const ushort* row = src + yy * 128;
            #pragma unroll
            for (int kx = 0; kx < 3; ++kx) {
                int xx = x + kx - 1;
                if ((unsigned)xx < 128u)
                    s = fmaf(wp[ky * 3 + kx], bf2f(row[xx]), s);
            }
        }
    }
    O[(long)ci * SPX + p] = f2bf(s);
}

// ---------------------------------------------------------------------------
// Gram + norms per (n,head): G[c][d] = sum_s q[c][s]*k[d][s] (fp32 from bf16);
// split-K over 32 chunks of 512, atomics.
// ---------------------------------------------------------------------------
__global__ __launch_bounds__(256) void gram48(
    const ushort* __restrict__ qkv, float* __restrict__ G,
    float* __restrict__ nq, float* __restrict__ nk)
{
    __shared__ float qs[48 * 132];
    __shared__ float ks[48 * 132];
    const int g = blockIdx.y;
    const int nb = g >> 3, h = g & 7;
    const long qb = ((long)nb * 1152 + h * 48) * SPX;
    const long kb = qb + 384L * SPX;
    const int tid = threadIdx.x;
    const int cg = tid >> 4, dg = tid & 15;
    float acc[3][3] = {};
    float nacc = 0.f;
    const int nc = tid % 48, nwhich = tid / 48;
    const int sch = blockIdx.x * 512;

    for (int sc = 0; sc < 4; ++sc) {
        const int sb = sch + sc * 128;
        __syncthreads();
        #pragma unroll
        for (int i = 0; i < 6; ++i) {
            int e = (i * 256 + tid) * 4;         // 6144 elems, 4/thread
            int c = e >> 7, s = e & 127;
            ushort4 uq = *(const ushort4*)&qkv[qb + (long)c * SPX + sb + s];
            ushort4 uk = *(const ushort4*)&qkv[kb + (long)c * SPX + sb + s];
            float4 fq = { bf2f(uq.x), bf2f(uq.y), bf2f(uq.z), bf2f(uq.w) };
            float4 fk = { bf2f(uk.x), bf2f(uk.y), bf2f(uk.z), bf2f(uk.w) };
            *(float4*)&qs[c * 132 + s] = fq;
            *(float4*)&ks[c * 132 + s] = fk;
        }
        __syncthreads();
        const float4* q0 = (const float4*)&qs[(cg * 3 + 0) * 132];
        const float4* q1 = (const float4*)&qs[(cg * 3 + 1) * 132];
        const float4* q2 = (const float4*)&qs[(cg * 3 + 2) * 132];
        const float4* k0 = (const float4*)&ks[(dg * 3 + 0) * 132];
        const float4* k1 = (const float4*)&ks[(dg * 3 + 1) * 132];
        const float4* k2 = (const float4*)&ks[(dg * 3 + 2) * 132];
        #pragma unroll 8
        for (int s4 = 0; s4 < 32; ++s4) {
            float4 qv[3] = { q0[s4], q1[s4], q2[s4] };
            float4 kv[3] = { k0[s4], k1[s4], k2[s4] };
            #pragma unroll
            for (int i = 0; i < 3; ++i)
                #pragma unroll
                for (int j = 0; j < 3; ++j)
                    acc[i][j] += qv[i].x * kv[j].x + qv[i].y * kv[j].y
                               + qv[i].z * kv[j].z + qv[i].w * kv[j].w;
        }
        if (tid < 96) {
            const float4* nr4 = (const float4*)((nwhich ? ks : qs) + nc * 132);
            #pragma unroll 8
            for (int s4 = 0; s4 < 32; ++s4) {
                float4 v = nr4[s4];
                nacc += v.x * v.x + v.y * v.y + v.z * v.z + v.w * v.w;
            }
        }
    }
    #pragma unroll
    for (int i = 0; i < 3; ++i)
        #pragma unroll
        for (int j = 0; j < 3; ++j)
            atomicAdd(&G[g * 2304 + (cg * 3 + i) * 48 + (dg * 3 + j)], acc[i][j]);
    if (tid < 96) atomicAdd((nwhich ? nk : nq) + g * 48 + nc, nacc);
}

// ---------------------------------------------------------------------------
// A[c][d] = softmax_d( G[c][d] / (max(|q_c|,eps)*max(|k_d|,eps)) * temp4[h] )
// ---------------------------------------------------------------------------
__global__ void attn_softmax48(const float* __restrict__ G, const float* __restrict__ nq,
                               const float* __restrict__ nk, const float* __restrict__ temp4,
                               float* __restrict__ A)
{
    const int g = blockIdx.x;
    const int c = threadIdx.x;
    if (c >= 48) return;
    const int h = g & 7;
    const float t = temp4[h];
    const float rq = 1.f / fmaxf(sqrtf(nq[g * 48 + c]), 1e-12f);
    float row[48];
    float mx = -1e30f;
    #pragma unroll
    for (int d = 0; d < 48; ++d) {
        float rk = 1.f / fmaxf(sqrtf(nk[g * 48 + d]), 1e-12f);
        float v = G[g * 2304 + c * 48 + d] * rq * rk * t;
        row[d] = v;
        mx = fmaxf(mx, v);
    }
    float sum = 0.f;
    #pragma unroll
    for (int d = 0; d < 48; ++d) { float e = expf(row[d] - mx); row[d] = e; sum += e; }
    const float inv = 1.f / sum;
    #pragma unroll
    for (int d = 0; d < 48; ++d) A[g * 2304 + c * 48 + d] = row[d] * inv;
}

// ---------------------------------------------------------------------------
// outT[nb][s][h*48+c] = sum_d A[c][d] * v[d][s]  (bf16 out, transposed layout)
// grid (64 s-tiles, 16 groups)
// ---------------------------------------------------------------------------
__global__ __launch_bounds__(256) void applyv48(
    const ushort* __restrict__ qkv, const float* __restrict__ A, ushort* __restrict__ outT)
{
    __shared__ float AT[48 * 52];     // AT[d][c]
    __shared__ float vs[48 * 256];
    const int g = blockIdx.y, tid = threadIdx.x;
    const int nb = g >> 3, h = g & 7;
    const long vb = ((long)nb * 1152 + 768 + h * 48) * SPX;
    const int s0 = blockIdx.x * 256;
    #pragma unroll
    for (int i = 0; i < 9; ++i) {
        int idx = tid + i * 256;                 // 2304
        int c = idx / 48, d = idx % 48;
        AT[d * 52 + c] = A[g * 2304 + idx];
    }
    #pragma unroll
    for (int i = 0; i < 12; ++i) {
        int e = (i * 256 + tid) * 4;             // 12288 elems, 4/thread
        int d = e >> 8, s = e & 255;
        ushort4 uv = *(const ushort4*)&qkv[vb + (long)d * SPX + s0 + s];
        float4 fv = { bf2f(uv.x), bf2f(uv.y), bf2f(uv.z), bf2f(uv.w) };
        *(float4*)&vs[d * 256 + s] = fv;
    }
    __syncthreads();
    const long ob = (long)nb * SPX * 384 + (long)(s0 + tid) * 384 + h * 48;
    for (int cg = 0; cg < 12; ++cg) {
        float a0 = 0.f, a1 = 0.f, a2 = 0.f, a3 = 0.f;
        #pragma unroll
        for (int d = 0; d < 48; ++d) {
            float vd = vs[d * 256 + tid];
            float4 av = *(const float4*)&AT[d * 52 + cg * 4];
            a0 = fmaf(av.x, vd, a0);
            a1 = fmaf(av.y, vd, a1);
            a2 = fmaf(av.z, vd, a2);
            a3 = fmaf(av.w, vd, a3);
        }
        ushort4 o = { f2bf(a0), f2bf(a1), f2bf(a2), f2bf(a3) };
        *(ushort4*)&outT[ob + cg * 4] = o;
    }
}

// ---------------------------------------------------------------------------
// Workspace (bytes):
//   XbT/outcT : [0, 25165824)            2*16384*384 bf16 (aliased; stage-disjoint)
//   Wqkvb     : [25165824, +884736)
//   Wprojb    : [26050560, +294912)
//   Y         : [26345472, +75497472)    2*1152*16384 bf16
//   QKV       : [101842944, +75497472)
//   G/NQ/NK/AAT: [177340416, +301056)
// total ~169.4 MiB
// ---------------------------------------------------------------------------
extern "C" void kernel_launch(void* const* d_in, const int* in_sizes, int n_in,
                              void* d_out, int out_size, void* d_ws, size_t ws_size,
                              hipStream_t stream)
{
    const float* x      = (const float*)d_in[0];
    const float* qkv_w  = (const float*)d_in[2];
    const float* dw_w   = (const float*)d_in[3];
    const float* proj_w = (const float*)d_in[4];
    const float* temp4  = (const float*)d_in[7];
    char* wsb = (char*)d_ws;
    float* out = (float*)d_out;

    ushort* XbT    = (ushort*)(wsb);
    ushort* Wqkvb  = (ushort*)(wsb + 25165824L);
    ushort* Wprojb = (ushort*)(wsb + 26050560L);
    ushort* Y      = (ushort*)(wsb + 26345472L);
    ushort* QKV    = (ushort*)(wsb + 101842944L);
    float*  G      = (float*)(wsb + 177340416L);
    float*  NQ     = G + 36864;
    float*  NK     = NQ + 768;
    float*  AAT    = NK + 768;
    ushort* outcT  = XbT;   // alias: XbT dead after qkv GEMM

    // stage 0: convert inputs
    transpose_cvt<<<dim3(512, 12, 2), 256, 0, stream>>>(x, XbT, 384, SPX);
    cvt_bf16<<<dim3(1728), 256, 0, stream>>>(qkv_w, Wqkvb, 1152 * 384);
    cvt_bf16<<<dim3(576), 256, 0, stream>>>(proj_w, Wprojb, 384 * 384);

    // stage 1: Y = qkv_w @ x  (bf16 MFMA), then depthwise 3x3 -> QKV
    gemm_bt<1><<<dim3(128, 9, 2), 256, 0, stream>>>(
        Wqkvb, XbT, Y, 1152, SPX, 384, (long)SPX * 384, (long)1152 * SPX, 1.0f);
    dwconv3x3<<<dim3(64, 2304), 256, 0, stream>>>(Y, dw_w, QKV);

    // stage 2-3: Gram + norms, cosine softmax
    hipMemsetAsync(G, 0, 153600, stream);
    gram48<<<dim3(32, 16), 256, 0, stream>>>(QKV, G, NQ, NK);
    attn_softmax48<<<dim3(16), dim3(64), 0, stream>>>(G, NQ, NK, temp4, AAT);

    // stage 4: outcT = (A @ v)^T  (bf16, [s][c] layout)
    applyv48<<<dim3(64, 16), 256, 0, stream>>>(QKV, AAT, outcT);

    // stage 5: out = 2 * (proj_w @ outc)  (fp32 out)
    gemm_bt<0><<<dim3(128, 3, 2), 256, 0, stream>>>(
        Wprojb, outcT, out, 384, SPX, 384, (long)SPX * 384, (long)384 * SPX, 2.0f);
}

// Round 4
// 344.325 us; speedup vs baseline: 2.7083x; 1.3660x over previous
//
#include <hip/hip_runtime.h>
#include <math.h>

#define SPX 16384   // H*W = 128*128

typedef unsigned short ushort_t;
typedef __attribute__((ext_vector_type(8))) short bf16x8;
typedef __attribute__((ext_vector_type(8))) unsigned short u16x8;
typedef __attribute__((ext_vector_type(4))) float f32x4;

static __device__ __forceinline__ ushort f2bf(float f) {
    union { float f; unsigned int u; } v; v.f = f;
    unsigned int r = v.u + 0x7FFFu + ((v.u >> 16) & 1u);   // RNE
    return (ushort)(r >> 16);
}
static __device__ __forceinline__ float bf2f(ushort u) {
    union { unsigned int u; float f; } v; v.u = ((unsigned int)u) << 16;
    return v.f;
}

// ---------------------------------------------------------------------------
// Transpose + convert: X[z][C][S] fp32 -> XT[z][S][C] bf16.  32x32 tiles.
// ---------------------------------------------------------------------------
__global__ __launch_bounds__(256) void transpose_cvt(
    const float* __restrict__ X, ushort* __restrict__ XT, int C, int S)
{
    __shared__ float t[32][33];
    const int s0 = blockIdx.x * 32, c0 = blockIdx.y * 32;
    const long zb = (long)blockIdx.z * C * S;
    const int tr = threadIdx.x >> 5, tc = threadIdx.x & 31;
    #pragma unroll
    for (int i = 0; i < 4; ++i) {
        int r = tr + i * 8;
        t[r][tc] = X[zb + (long)(c0 + r) * S + s0 + tc];
    }
    __syncthreads();
    #pragma unroll
    for (int i = 0; i < 4; ++i) {
        int r = tr + i * 8;     // s index within tile
        XT[zb + (long)(s0 + r) * C + c0 + tc] = f2bf(t[tc][r]);
    }
}

// ---------------------------------------------------------------------------
// Elementwise fp32 -> bf16 (weights)
// ---------------------------------------------------------------------------
__global__ __launch_bounds__(256) void cvt_bf16(
    const float* __restrict__ in, ushort* __restrict__ out, int n)
{
    int i = blockIdx.x * 256 + threadIdx.x;
    if (i < n) out[i] = f2bf(in[i]);
}

// ---------------------------------------------------------------------------
// bf16 MFMA GEMM (B-transposed input):
//   C[z][m][n] = alpha * sum_k A[m][k] * BT[z][n][k]
// 128x128 tile, BK=32, 256 threads (4 waves 2x2), 16x16x32 MFMA.
// ---------------------------------------------------------------------------
template<int OUT_BF16>
__global__ __launch_bounds__(256) void gemm_bt(
    const ushort* __restrict__ A, const ushort* __restrict__ BT,
    void* __restrict__ Cv, int M, int N, int K, long sB, long sC, float alpha)
{
    __shared__ ushort As[128 * 32];
    __shared__ ushort Bs[128 * 32];
    const int tid = threadIdx.x;
    const int w = tid >> 6;
    const int wr = w >> 1, wc = w & 1;
    const int lane = tid & 63;
    const int grp = lane >> 4, lr = lane & 15;
    const int m0 = blockIdx.y * 128, n0 = blockIdx.x * 128;
    const char* Ab = (const char*)A;
    const char* Bb = (const char*)(BT + (long)blockIdx.z * sB);

    f32x4 acc[4][4] = {};

    for (int k0 = 0; k0 < K; k0 += 32) {
        #pragma unroll
        for (int i = 0; i < 2; ++i) {
            const int o = (i * 256 + tid) * 16;   // byte offset within 8 KB tile
            const int row = o >> 6, kb = o & 63;  // 64 B per tile row (32 bf16)
            const char* ga = Ab + ((long)(m0 + row) * K + k0) * 2 + kb;
            const char* gb = Bb + ((long)(n0 + row) * K + k0) * 2 + kb;
            __builtin_amdgcn_global_load_lds(
                (const __attribute__((address_space(1))) unsigned int*)ga,
                (__attribute__((address_space(3))) unsigned int*)((char*)As + o), 16, 0, 0);
            __builtin_amdgcn_global_load_lds(
                (const __attribute__((address_space(1))) unsigned int*)gb,
                (__attribute__((address_space(3))) unsigned int*)((char*)Bs + o), 16, 0, 0);
        }
        __syncthreads();
        bf16x8 av[4], bv[4];
        #pragma unroll
        for (int mi = 0; mi < 4; ++mi)
            av[mi] = *(const bf16x8*)&As[(wr * 64 + mi * 16 + lr) * 32 + grp * 8];
        #pragma unroll
        for (int ni = 0; ni < 4; ++ni)
            bv[ni] = *(const bf16x8*)&Bs[(wc * 64 + ni * 16 + lr) * 32 + grp * 8];
        #pragma unroll
        for (int mi = 0; mi < 4; ++mi)
            #pragma unroll
            for (int ni = 0; ni < 4; ++ni)
                acc[mi][ni] = __builtin_amdgcn_mfma_f32_16x16x32_bf16(
                    av[mi], bv[ni], acc[mi][ni], 0, 0, 0);
        __syncthreads();
    }

    const long cb = (long)blockIdx.z * sC;
    #pragma unroll
    for (int mi = 0; mi < 4; ++mi) {
        #pragma unroll
        for (int ni = 0; ni < 4; ++ni) {
            const int r0 = m0 + wr * 64 + mi * 16 + grp * 4;
            const int c  = n0 + wc * 64 + ni * 16 + lr;
            #pragma unroll
            for (int j = 0; j < 4; ++j) {
                float vv = acc[mi][ni][j] * alpha;
                if (OUT_BF16) ((ushort*)Cv)[cb + (long)(r0 + j) * N + c] = f2bf(vv);
                else          ((float*)Cv)[cb + (long)(r0 + j) * N + c] = vv;
            }
        }
    }
}

// ---------------------------------------------------------------------------
// Depthwise 3x3, SAME (zero pad), H=W=128, bf16 in/out, fp32 weights.
// Vectorized: one block = (channel, 16-row group). Stage 18 halo rows in LDS
// (branch-free inner loop via zero-padded columns); ushort8 loads/stores.
// ---------------------------------------------------------------------------
__global__ __launch_bounds__(256) void dwconv3x3v(
    const ushort* __restrict__ Y, const float* __restrict__ Wd, ushort* __restrict__ O)
{
    __shared__ ushort rows[18][144];   // data cols 8..135; pads at 7 and 136
    const int ci = blockIdx.y;
    const int y0 = blockIdx.x * 16;
    const int tid = threadIdx.x;
    const ushort* __restrict__ src = Y + (long)ci * SPX;
    const float* wp = Wd + (ci % 1152) * 9;

    // stage 18 rows (with vertical zero halo)
    #pragma unroll
    for (int it = 0; it < 2; ++it) {
        int ch = tid + it * 256;
        if (ch < 288) {
            int r = ch >> 4, xc = ch & 15;
            int gy = y0 + r - 1;
            u16x8 v;
            if ((unsigned)gy < 128u)
                v = *(const u16x8*)&src[gy * 128 + xc * 8];
            else
                v = (u16x8)0;
            *(u16x8*)&rows[r][8 + xc * 8] = v;
        }
    }
    // horizontal zero pads
    if (tid < 18) { rows[tid][7] = 0; rows[tid][136] = 0; }
    __syncthreads();

    float w00 = wp[0], w01 = wp[1], w02 = wp[2];
    float w10 = wp[3], w11 = wp[4], w12 = wp[5];
    float w20 = wp[6], w21 = wp[7], w22 = wp[8];

    const int r = tid >> 4, xc = tid & 15;   // output row r (0..15), col chunk
    const int xb = 7 + xc * 8;               // LDS col of x-1 for first output
    float a[3][10];
    #pragma unroll
    for (int dy = 0; dy < 3; ++dy)
        #pragma unroll
        for (int i = 0; i < 10; ++i)
            a[dy][i] = bf2f(rows[r + dy][xb + i]);

    ushort o[8];
    #pragma unroll
    for (int j = 0; j < 8; ++j) {
        float s = w00 * a[0][j] + w01 * a[0][j + 1] + w02 * a[0][j + 2]
                + w10 * a[1][j] + w11 * a[1][j + 1] + w12 * a[1][j + 2]
                + w20 * a[2][j] + w21 * a[2][j + 1] + w22 * a[2][j + 2];
        o[j] = f2bf(s);
    }
    *(u16x8*)&O[(long)ci * SPX + (y0 + r) * 128 + xc * 8] = *(u16x8*)o;
}

// ---------------------------------------------------------------------------
// Gram + norms per (n,head): G[c][d] = sum_s q[c][s]*k[d][s] (fp32 from bf16);
// split-K over 32 chunks of 512, atomics.
// ---------------------------------------------------------------------------
__global__ __launch_bounds__(256) void gram48(
    const ushort* __restrict__ qkv, float* __restrict__ G,
    float* __restrict__ nq, float* __restrict__ nk)
{
    __shared__ float qs[48 * 132];
    __shared__ float ks[48 * 132];
    const int g = blockIdx.y;
    const int nb = g >> 3, h = g & 7;
    const long qb = ((long)nb * 1152 + h * 48) * SPX;
    const long kb = qb + 384L * SPX;
    const int tid = threadIdx.x;
    const int cg = tid >> 4, dg = tid & 15;
    float acc[3][3] = {};
    float nacc = 0.f;
    const int nc = tid % 48, nwhich = tid / 48;
    const int sch = blockIdx.x * 512;

    for (int sc = 0; sc < 4; ++sc) {
        const int sb = sch + sc * 128;
        __syncthreads();
        #pragma unroll
        for (int i = 0; i < 6; ++i) {
            int e = (i * 256 + tid) * 4;         // 6144 elems, 4/thread
            int c = e >> 7, s = e & 127;
            ushort4 uq = *(const ushort4*)&qkv[qb + (long)c * SPX + sb + s];
            ushort4 uk = *(const ushort4*)&qkv[kb + (long)c * SPX + sb + s];
            float4 fq = { bf2f(uq.x), bf2f(uq.y), bf2f(uq.z), bf2f(uq.w) };
            float4 fk = { bf2f(uk.x), bf2f(uk.y), bf2f(uk.z), bf2f(uk.w) };
            *(float4*)&qs[c * 132 + s] = fq;
            *(float4*)&ks[c * 132 + s] = fk;
        }
        __syncthreads();
        const float4* q0 = (const float4*)&qs[(cg * 3 + 0) * 132];
        const float4* q1 = (const float4*)&qs[(cg * 3 + 1) * 132];
        const float4* q2 = (const float4*)&qs[(cg * 3 + 2) * 132];
        const float4* k0 = (const float4*)&ks[(dg * 3 + 0) * 132];
        const float4* k1 = (const float4*)&ks[(dg * 3 + 1) * 132];
        const float4* k2 = (const float4*)&ks[(dg * 3 + 2) * 132];
        #pragma unroll 8
        for (int s4 = 0; s4 < 32; ++s4) {
            float4 qv[3] = { q0[s4], q1[s4], q2[s4] };
            float4 kv[3] = { k0[s4], k1[s4], k2[s4] };
            #pragma unroll
            for (int i = 0; i < 3; ++i)
                #pragma unroll
                for (int j = 0; j < 3; ++j)
                    acc[i][j] += qv[i].x * kv[j].x + qv[i].y * kv[j].y
                               + qv[i].z * kv[j].z + qv[i].w * kv[j].w;
        }
        if (tid < 96) {
            const float4* nr4 = (const float4*)((nwhich ? ks : qs) + nc * 132);
            #pragma unroll 8
            for (int s4 = 0; s4 < 32; ++s4) {
                float4 v = nr4[s4];
                nacc += v.x * v.x + v.y * v.y + v.z * v.z + v.w * v.w;
            }
        }
    }
    #pragma unroll
    for (int i = 0; i < 3; ++i)
        #pragma unroll
        for (int j = 0; j < 3; ++j)
            atomicAdd(&G[g * 2304 + (cg * 3 + i) * 48 + (dg * 3 + j)], acc[i][j]);
    if (tid < 96) atomicAdd((nwhich ? nk : nq) + g * 48 + nc, nacc);
}

// ---------------------------------------------------------------------------
// A[c][d] = softmax_d( G[c][d] / (max(|q_c|,eps)*max(|k_d|,eps)) * temp4[h] )
// ---------------------------------------------------------------------------
__global__ void attn_softmax48(const float* __restrict__ G, const float* __restrict__ nq,
                               const float* __restrict__ nk, const float* __restrict__ temp4,
                               float* __restrict__ A)
{
    const int g = blockIdx.x;
    const int c = threadIdx.x;
    if (c >= 48) return;
    const int h = g & 7;
    const float t = temp4[h];
    const float rq = 1.f / fmaxf(sqrtf(nq[g * 48 + c]), 1e-12f);
    float row[48];
    float mx = -1e30f;
    #pragma unroll
    for (int d = 0; d < 48; ++d) {
        float rk = 1.f / fmaxf(sqrtf(nk[g * 48 + d]), 1e-12f);
        float v = G[g * 2304 + c * 48 + d] * rq * rk * t;
        row[d] = v;
        mx = fmaxf(mx, v);
    }
    float sum = 0.f;
    #pragma unroll
    for (int d = 0; d < 48; ++d) { float e = expf(row[d] - mx); row[d] = e; sum += e; }
    const float inv = 1.f / sum;
    #pragma unroll
    for (int d = 0; d < 48; ++d) A[g * 2304 + c * 48 + d] = row[d] * inv;
}

// ---------------------------------------------------------------------------
// outT[nb][s][h*48+c] = sum_d A[c][d] * v[d][s]  (bf16 out, transposed layout)
// ---------------------------------------------------------------------------
__global__ __launch_bounds__(256) void applyv48(
    const ushort* __restrict__ qkv, const float* __restrict__ A, ushort* __restrict__ outT)
{
    __shared__ float AT[48 * 52];     // AT[d][c]
    __shared__ float vs[48 * 256];
    const int g = blockIdx.y, tid = threadIdx.x;
    const int nb = g >> 3, h = g & 7;
    const long vb = ((long)nb * 1152 + 768 + h * 48) * SPX;
    const int s0 = blockIdx.x * 256;
    #pragma unroll
    for (int i = 0; i < 9; ++i) {
        int idx = tid + i * 256;                 // 2304
        int c = idx / 48, d = idx % 48;
        AT[d * 52 + c] = A[g * 2304 + idx];
    }
    #pragma unroll
    for (int i = 0; i < 12; ++i) {
        int e = (i * 256 + tid) * 4;             // 12288 elems, 4/thread
        int d = e >> 8, s = e & 255;
        ushort4 uv = *(const ushort4*)&qkv[vb + (long)d * SPX + s0 + s];
        float4 fv = { bf2f(uv.x), bf2f(uv.y), bf2f(uv.z), bf2f(uv.w) };
        *(float4*)&vs[d * 256 + s] = fv;
    }
    __syncthreads();
    const long ob = (long)nb * SPX * 384 + (long)(s0 + tid) * 384 + h * 48;
    for (int cg = 0; cg < 12; ++cg) {
        float a0 = 0.f, a1 = 0.f, a2 = 0.f, a3 = 0.f;
        #pragma unroll
        for (int d = 0; d < 48; ++d) {
            float vd = vs[d * 256 + tid];
            float4 av = *(const float4*)&AT[d * 52 + cg * 4];
            a0 = fmaf(av.x, vd, a0);
            a1 = fmaf(av.y, vd, a1);
            a2 = fmaf(av.z, vd, a2);
            a3 = fmaf(av.w, vd, a3);
        }
        ushort4 o = { f2bf(a0), f2bf(a1), f2bf(a2), f2bf(a3) };
        *(ushort4*)&outT[ob + cg * 4] = o;
    }
}

// ---------------------------------------------------------------------------
// Workspace (bytes):
//   XbT/outcT : [0, 25165824)            2*16384*384 bf16 (aliased; stage-disjoint)
//   Wqkvb     : [25165824, +884736)
//   Wprojb    : [26050560, +294912)
//   Y         : [26345472, +75497472)    2*1152*16384 bf16
//   QKV       : [101842944, +75497472)
//   G/NQ/NK/AAT: [177340416, +301056)
// total ~169.4 MiB
// ---------------------------------------------------------------------------
extern "C" void kernel_launch(void* const* d_in, const int* in_sizes, int n_in,
                              void* d_out, int out_size, void* d_ws, size_t ws_size,
                              hipStream_t stream)
{
    const float* x      = (const float*)d_in[0];
    const float* qkv_w  = (const float*)d_in[2];
    const float* dw_w   = (const float*)d_in[3];
    const float* proj_w = (const float*)d_in[4];
    const float* temp4  = (const float*)d_in[7];
    char* wsb = (char*)d_ws;
    float* out = (float*)d_out;

    ushort* XbT    = (ushort*)(wsb);
    ushort* Wqkvb  = (ushort*)(wsb + 25165824L);
    ushort* Wprojb = (ushort*)(wsb + 26050560L);
    ushort* Y      = (ushort*)(wsb + 26345472L);
    ushort* QKV    = (ushort*)(wsb + 101842944L);
    float*  G      = (float*)(wsb + 177340416L);
    float*  NQ     = G + 36864;
    float*  NK     = NQ + 768;
    float*  AAT    = NK + 768;
    ushort* outcT  = XbT;   // alias: XbT dead after qkv GEMM

    // stage 0: convert inputs
    transpose_cvt<<<dim3(512, 12, 2), 256, 0, stream>>>(x, XbT, 384, SPX);
    cvt_bf16<<<dim3(1728), 256, 0, stream>>>(qkv_w, Wqkvb, 1152 * 384);
    cvt_bf16<<<dim3(576), 256, 0, stream>>>(proj_w, Wprojb, 384 * 384);

    // stage 1: Y = qkv_w @ x  (bf16 MFMA), then depthwise 3x3 -> QKV
    gemm_bt<1><<<dim3(128, 9, 2), 256, 0, stream>>>(
        Wqkvb, XbT, Y, 1152, SPX, 384, (long)SPX * 384, (long)1152 * SPX, 1.0f);
    dwconv3x3v<<<dim3(8, 2304), 256, 0, stream>>>(Y, dw_w, QKV);

    // stage 2-3: Gram + norms, cosine softmax
    hipMemsetAsync(G, 0, 153600, stream);
    gram48<<<dim3(32, 16), 256, 0, stream>>>(QKV, G, NQ, NK);
    attn_softmax48<<<dim3(16), dim3(64), 0, stream>>>(G, NQ, NK, temp4, AAT);

    // stage 4: outcT = (A @ v)^T  (bf16, [s][c] layout)
    applyv48<<<dim3(64, 16), 256, 0, stream>>>(QKV, AAT, outcT);

    // stage 5: out = 2 * (proj_w @ outc)  (fp32 out)
    gemm_bt<0><<<dim3(128, 3, 2), 256, 0, stream>>>(
        Wprojb, outcT, out, 384, SPX, 384, (long)SPX * 384, (long)384 * SPX, 2.0f);
}

// Round 5
// 323.028 us; speedup vs baseline: 2.8869x; 1.0659x over previous
//
#include <hip/hip_runtime.h>
#include <math.h>

#define SPX 16384   // H*W = 128*128

typedef unsigned short ushort_t;
typedef __attribute__((ext_vector_type(8))) short bf16x8;
typedef __attribute__((ext_vector_type(8))) unsigned short u16x8;
typedef __attribute__((ext_vector_type(4))) float f32x4;

static __device__ __forceinline__ ushort f2bf(float f) {
    union { float f; unsigned int u; } v; v.f = f;
    unsigned int r = v.u + 0x7FFFu + ((v.u >> 16) & 1u);   // RNE
    return (ushort)(r >> 16);
}
static __device__ __forceinline__ float bf2f(ushort u) {
    union { unsigned int u; float f; } v; v.u = ((unsigned int)u) << 16;
    return v.f;
}

// ---------------------------------------------------------------------------
// Transpose + convert: X[z][C][S] fp32 -> XT[z][S][C] bf16.  64x64 tiles,
// float4 coalesced loads, u16x8 16B stores.
// ---------------------------------------------------------------------------
__global__ __launch_bounds__(256) void transpose_cvt64(
    const float* __restrict__ X, ushort* __restrict__ XT, int C, int S)
{
    __shared__ float t[64 * 68];
    const int s0 = blockIdx.x * 64, c0 = blockIdx.y * 64;
    const long zb = (long)blockIdx.z * C * S;
    const int tid = threadIdx.x;
    const int cl = tid >> 4, sw = tid & 15;
    #pragma unroll
    for (int i = 0; i < 4; ++i) {
        int c = cl + 16 * i;
        float4 v = *(const float4*)&X[zb + (long)(c0 + c) * S + s0 + sw * 4];
        *(float4*)&t[c * 68 + sw * 4] = v;
    }
    __syncthreads();
    const int sr = tid >> 2, cq = tid & 3;
    #pragma unroll
    for (int i = 0; i < 2; ++i) {
        int cg = cq + 4 * i;
        ushort o[8];
        #pragma unroll
        for (int j = 0; j < 8; ++j) o[j] = f2bf(t[(cg * 8 + j) * 68 + sr]);
        *(u16x8*)&XT[zb + (long)(s0 + sr) * C + c0 + cg * 8] = *(u16x8*)o;
    }
}

// ---------------------------------------------------------------------------
// Elementwise fp32 -> bf16 (weights)
// ---------------------------------------------------------------------------
__global__ __launch_bounds__(256) void cvt_bf16(
    const float* __restrict__ in, ushort* __restrict__ out, int n)
{
    int i = blockIdx.x * 256 + threadIdx.x;
    if (i < n) out[i] = f2bf(in[i]);
}

// ---------------------------------------------------------------------------
// bf16 MFMA GEMM (B-transposed input):
//   C[z][m][n] = alpha * sum_k A[m][k] * BT[z][n][k]
// 128x128 tile, BK=32, 256 threads (4 waves 2x2), 16x16x32 MFMA.
// ---------------------------------------------------------------------------
template<int OUT_BF16>
__global__ __launch_bounds__(256) void gemm_bt(
    const ushort* __restrict__ A, const ushort* __restrict__ BT,
    void* __restrict__ Cv, int M, int N, int K, long sB, long sC, float alpha)
{
    __shared__ ushort As[128 * 32];
    __shared__ ushort Bs[128 * 32];
    const int tid = threadIdx.x;
    const int w = tid >> 6;
    const int wr = w >> 1, wc = w & 1;
    const int lane = tid & 63;
    const int grp = lane >> 4, lr = lane & 15;
    const int m0 = blockIdx.y * 128, n0 = blockIdx.x * 128;
    const char* Ab = (const char*)A;
    const char* Bb = (const char*)(BT + (long)blockIdx.z * sB);

    f32x4 acc[4][4] = {};

    for (int k0 = 0; k0 < K; k0 += 32) {
        #pragma unroll
        for (int i = 0; i < 2; ++i) {
            const int o = (i * 256 + tid) * 16;   // byte offset within 8 KB tile
            const int row = o >> 6, kb = o & 63;  // 64 B per tile row (32 bf16)
            const char* ga = Ab + ((long)(m0 + row) * K + k0) * 2 + kb;
            const char* gb = Bb + ((long)(n0 + row) * K + k0) * 2 + kb;
            __builtin_amdgcn_global_load_lds(
                (const __attribute__((address_space(1))) unsigned int*)ga,
                (__attribute__((address_space(3))) unsigned int*)((char*)As + o), 16, 0, 0);
            __builtin_amdgcn_global_load_lds(
                (const __attribute__((address_space(1))) unsigned int*)gb,
                (__attribute__((address_space(3))) unsigned int*)((char*)Bs + o), 16, 0, 0);
        }
        __syncthreads();
        bf16x8 av[4], bv[4];
        #pragma unroll
        for (int mi = 0; mi < 4; ++mi)
            av[mi] = *(const bf16x8*)&As[(wr * 64 + mi * 16 + lr) * 32 + grp * 8];
        #pragma unroll
        for (int ni = 0; ni < 4; ++ni)
            bv[ni] = *(const bf16x8*)&Bs[(wc * 64 + ni * 16 + lr) * 32 + grp * 8];
        #pragma unroll
        for (int mi = 0; mi < 4; ++mi)
            #pragma unroll
            for (int ni = 0; ni < 4; ++ni)
                acc[mi][ni] = __builtin_amdgcn_mfma_f32_16x16x32_bf16(
                    av[mi], bv[ni], acc[mi][ni], 0, 0, 0);
        __syncthreads();
    }

    const long cb = (long)blockIdx.z * sC;
    #pragma unroll
    for (int mi = 0; mi < 4; ++mi) {
        #pragma unroll
        for (int ni = 0; ni < 4; ++ni) {
            const int r0 = m0 + wr * 64 + mi * 16 + grp * 4;
            const int c  = n0 + wc * 64 + ni * 16 + lr;
            #pragma unroll
            for (int j = 0; j < 4; ++j) {
                float vv = acc[mi][ni][j] * alpha;
                if (OUT_BF16) ((ushort*)Cv)[cb + (long)(r0 + j) * N + c] = f2bf(vv);
                else          ((float*)Cv)[cb + (long)(r0 + j) * N + c] = vv;
            }
        }
    }
}

// ---------------------------------------------------------------------------
// Depthwise 3x3, SAME (zero pad), H=W=128, bf16 in/out, fp32 weights.
// Block = (channel, 64-row group); thread = 4x8 output tile.
// LDS 66 rows x pitch 152 (bank-stagger); window via 3 aligned ds_read_b128.
// ---------------------------------------------------------------------------
__global__ __launch_bounds__(256) void dwconv3x3v2(
    const ushort* __restrict__ Y, const float* __restrict__ Wd, ushort* __restrict__ O)
{
    __shared__ ushort rows[66 * 152];   // data at cols 8..135; zero pads at 7,136
    const int ci = blockIdx.y;
    const int y0 = blockIdx.x * 64;
    const int tid = threadIdx.x;
    const ushort* __restrict__ src = Y + (long)ci * SPX;
    const float* wp = Wd + (ci % 1152) * 9;

    for (int ch = tid; ch < 1056; ch += 256) {   // 66 rows x 16 chunks
        int r = ch >> 4, xcs = ch & 15;
        int gy = y0 + r - 1;
        u16x8 v;
        if ((unsigned)gy < 128u) v = *(const u16x8*)&src[gy * 128 + xcs * 8];
        else                     v = (u16x8)0;
        *(u16x8*)&rows[r * 152 + 8 + xcs * 8] = v;
    }
    if (tid < 66) { rows[tid * 152 + 7] = 0; rows[tid * 152 + 136] = 0; }
    __syncthreads();

    const float w00 = wp[0], w01 = wp[1], w02 = wp[2];
    const float w10 = wp[3], w11 = wp[4], w12 = wp[5];
    const float w20 = wp[6], w21 = wp[7], w22 = wp[8];

    const int ry = tid >> 4, xc = tid & 15;
    float acc[4][8] = {};
    #pragma unroll
    for (int ir = 0; ir < 6; ++ir) {
        const int t = 4 * ry + ir;
        const ushort* rb = &rows[t * 152 + xc * 8];
        u16x8 c0 = *(const u16x8*)(rb);        // LDS cols 8xc..8xc+7 (need [7])
        u16x8 c1 = *(const u16x8*)(rb + 8);    // LDS cols 8xc+8..+15 (all)
        u16x8 c2 = *(const u16x8*)(rb + 16);   // LDS cols 8xc+16..   (need [0])
        float win[10];
        win[0] = bf2f(c0[7]);
        #pragma unroll
        for (int j = 0; j < 8; ++j) win[j + 1] = bf2f(c1[j]);
        win[9] = bf2f(c2[0]);
        if (ir >= 2) {
            #pragma unroll
            for (int j = 0; j < 8; ++j)
                acc[ir - 2][j] += w20 * win[j] + w21 * win[j + 1] + w22 * win[j + 2];
        }
        if (ir >= 1 && ir <= 4) {
            #pragma unroll
            for (int j = 0; j < 8; ++j)
                acc[ir - 1][j] += w10 * win[j] + w11 * win[j + 1] + w12 * win[j + 2];
        }
        if (ir <= 3) {
            #pragma unroll
            for (int j = 0; j < 8; ++j)
                acc[ir][j] += w00 * win[j] + w01 * win[j + 1] + w02 * win[j + 2];
        }
    }
    #pragma unroll
    for (int q = 0; q < 4; ++q) {
        ushort o[8];
        #pragma unroll
        for (int j = 0; j < 8; ++j) o[j] = f2bf(acc[q][j]);
        *(u16x8*)&O[(long)ci * SPX + (y0 + 4 * ry + q) * 128 + xc * 8] = *(u16x8*)o;
    }
}

// ---------------------------------------------------------------------------
// Gram + norms per (n,head): G[c][d] = sum_s q[c][s]*k[d][s] (fp32 from bf16);
// split-K over 32 chunks of 512, atomics.
// ---------------------------------------------------------------------------
__global__ __launch_bounds__(256) void gram48(
    const ushort* __restrict__ qkv, float* __restrict__ G,
    float* __restrict__ nq, float* __restrict__ nk)
{
    __shared__ float qs[48 * 132];
    __shared__ float ks[48 * 132];
    const int g = blockIdx.y;
    const int nb = g >> 3, h = g & 7;
    const long qb = ((long)nb * 1152 + h * 48) * SPX;
    const long kb = qb + 384L * SPX;
    const int tid = threadIdx.x;
    const int cg = tid >> 4, dg = tid & 15;
    float acc[3][3] = {};
    float nacc = 0.f;
    const int nc = tid % 48, nwhich = tid / 48;
    const int sch = blockIdx.x * 512;

    for (int sc = 0; sc < 4; ++sc) {
        const int sb = sch + sc * 128;
        __syncthreads();
        #pragma unroll
        for (int i = 0; i < 6; ++i) {
            int e = (i * 256 + tid) * 4;         // 6144 elems, 4/thread
            int c = e >> 7, s = e & 127;
            ushort4 uq = *(const ushort4*)&qkv[qb + (long)c * SPX + sb + s];
            ushort4 uk = *(const ushort4*)&qkv[kb + (long)c * SPX + sb + s];
            float4 fq = { bf2f(uq.x), bf2f(uq.y), bf2f(uq.z), bf2f(uq.w) };
            float4 fk = { bf2f(uk.x), bf2f(uk.y), bf2f(uk.z), bf2f(uk.w) };
            *(float4*)&qs[c * 132 + s] = fq;
            *(float4*)&ks[c * 132 + s] = fk;
        }
        __syncthreads();
        const float4* q0 = (const float4*)&qs[(cg * 3 + 0) * 132];
        const float4* q1 = (const float4*)&qs[(cg * 3 + 1) * 132];
        const float4* q2 = (const float4*)&qs[(cg * 3 + 2) * 132];
        const float4* k0 = (const float4*)&ks[(dg * 3 + 0) * 132];
        const float4* k1 = (const float4*)&ks[(dg * 3 + 1) * 132];
        const float4* k2 = (const float4*)&ks[(dg * 3 + 2) * 132];
        #pragma unroll 8
        for (int s4 = 0; s4 < 32; ++s4) {
            float4 qv[3] = { q0[s4], q1[s4], q2[s4] };
            float4 kv[3] = { k0[s4], k1[s4], k2[s4] };
            #pragma unroll
            for (int i = 0; i < 3; ++i)
                #pragma unroll
                for (int j = 0; j < 3; ++j)
                    acc[i][j] += qv[i].x * kv[j].x + qv[i].y * kv[j].y
                               + qv[i].z * kv[j].z + qv[i].w * kv[j].w;
        }
        if (tid < 96) {
            const float4* nr4 = (const float4*)((nwhich ? ks : qs) + nc * 132);
            #pragma unroll 8
            for (int s4 = 0; s4 < 32; ++s4) {
                float4 v = nr4[s4];
                nacc += v.x * v.x + v.y * v.y + v.z * v.z + v.w * v.w;
            }
        }
    }
    #pragma unroll
    for (int i = 0; i < 3; ++i)
        #pragma unroll
        for (int j = 0; j < 3; ++j)
            atomicAdd(&G[g * 2304 + (cg * 3 + i) * 48 + (dg * 3 + j)], acc[i][j]);
    if (tid < 96) atomicAdd((nwhich ? nk : nq) + g * 48 + nc, nacc);
}

// ---------------------------------------------------------------------------
// A[c][d] = softmax_d( G[c][d] / (max(|q_c|,eps)*max(|k_d|,eps)) * temp4[h] )
// ---------------------------------------------------------------------------
__global__ void attn_softmax48(const float* __restrict__ G, const float* __restrict__ nq,
                               const float* __restrict__ nk, const float* __restrict__ temp4,
                               float* __restrict__ A)
{
    const int g = blockIdx.x;
    const int c = threadIdx.x;
    if (c >= 48) return;
    const int h = g & 7;
    const float t = temp4[h];
    const float rq = 1.f / fmaxf(sqrtf(nq[g * 48 + c]), 1e-12f);
    float row[48];
    float mx = -1e30f;
    #pragma unroll
    for (int d = 0; d < 48; ++d) {
        float rk = 1.f / fmaxf(sqrtf(nk[g * 48 + d]), 1e-12f);
        float v = G[g * 2304 + c * 48 + d] * rq * rk * t;
        row[d] = v;
        mx = fmaxf(mx, v);
    }
    float sum = 0.f;
    #pragma unroll
    for (int d = 0; d < 48; ++d) { float e = expf(row[d] - mx); row[d] = e; sum += e; }
    const float inv = 1.f / sum;
    #pragma unroll
    for (int d = 0; d < 48; ++d) A[g * 2304 + c * 48 + d] = row[d] * inv;
}

// ---------------------------------------------------------------------------
// outT[nb][s][h*48+c] = sum_d A[c][d] * v[d][s]  (bf16 out, transposed layout)
// ---------------------------------------------------------------------------
__global__ __launch_bounds__(256) void applyv48(
    const ushort* __restrict__ qkv, const float* __restrict__ A, ushort* __restrict__ outT)
{
    __shared__ float AT[48 * 52];     // AT[d][c]
    __shared__ float vs[48 * 256];
    const int g = blockIdx.y, tid = threadIdx.x;
    const int nb = g >> 3, h = g & 7;
    const long vb = ((long)nb * 1152 + 768 + h * 48) * SPX;
    const int s0 = blockIdx.x * 256;
    #pragma unroll
    for (int i = 0; i < 9; ++i) {
        int idx = tid + i * 256;                 // 2304
        int c = idx / 48, d = idx % 48;
        AT[d * 52 + c] = A[g * 2304 + idx];
    }
    #pragma unroll
    for (int i = 0; i < 12; ++i) {
        int e = (i * 256 + tid) * 4;             // 12288 elems, 4/thread
        int d = e >> 8, s = e & 255;
        ushort4 uv = *(const ushort4*)&qkv[vb + (long)d * SPX + s0 + s];
        float4 fv = { bf2f(uv.x), bf2f(uv.y), bf2f(uv.z), bf2f(uv.w) };
        *(float4*)&vs[d * 256 + s] = fv;
    }
    __syncthreads();
    const long ob = (long)nb * SPX * 384 + (long)(s0 + tid) * 384 + h * 48;
    for (int cg = 0; cg < 12; ++cg) {
        float a0 = 0.f, a1 = 0.f, a2 = 0.f, a3 = 0.f;
        #pragma unroll
        for (int d = 0; d < 48; ++d) {
            float vd = vs[d * 256 + tid];
            float4 av = *(const float4*)&AT[d * 52 + cg * 4];
            a0 = fmaf(av.x, vd, a0);
            a1 = fmaf(av.y, vd, a1);
            a2 = fmaf(av.z, vd, a2);
            a3 = fmaf(av.w, vd, a3);
        }
        ushort4 o = { f2bf(a0), f2bf(a1), f2bf(a2), f2bf(a3) };
        *(ushort4*)&outT[ob + cg * 4] = o;
    }
}

// ---------------------------------------------------------------------------
// Workspace (bytes):
//   XbT/outcT : [0, 25165824)            2*16384*384 bf16 (aliased; stage-disjoint)
//   Wqkvb     : [25165824, +884736)
//   Wprojb    : [26050560, +294912)
//   Y         : [26345472, +75497472)    2*1152*16384 bf16
//   QKV       : [101842944, +75497472)
//   G/NQ/NK/AAT: [177340416, +301056)
// total ~169.4 MiB
// ---------------------------------------------------------------------------
extern "C" void kernel_launch(void* const* d_in, const int* in_sizes, int n_in,
                              void* d_out, int out_size, void* d_ws, size_t ws_size,
                              hipStream_t stream)
{
    const float* x      = (const float*)d_in[0];
    const float* qkv_w  = (const float*)d_in[2];
    const float* dw_w   = (const float*)d_in[3];
    const float* proj_w = (const float*)d_in[4];
    const float* temp4  = (const float*)d_in[7];
    char* wsb = (char*)d_ws;
    float* out = (float*)d_out;

    ushort* XbT    = (ushort*)(wsb);
    ushort* Wqkvb  = (ushort*)(wsb + 25165824L);
    ushort* Wprojb = (ushort*)(wsb + 26050560L);
    ushort* Y      = (ushort*)(wsb + 26345472L);
    ushort* QKV    = (ushort*)(wsb + 101842944L);
    float*  G      = (float*)(wsb + 177340416L);
    float*  NQ     = G + 36864;
    float*  NK     = NQ + 768;
    float*  AAT    = NK + 768;
    ushort* outcT  = XbT;   // alias: XbT dead after qkv GEMM

    // stage 0: convert inputs
    transpose_cvt64<<<dim3(256, 6, 2), 256, 0, stream>>>(x, XbT, 384, SPX);
    cvt_bf16<<<dim3(1728), 256, 0, stream>>>(qkv_w, Wqkvb, 1152 * 384);
    cvt_bf16<<<dim3(576), 256, 0, stream>>>(proj_w, Wprojb, 384 * 384);

    // stage 1: Y = qkv_w @ x  (bf16 MFMA), then depthwise 3x3 -> QKV
    gemm_bt<1><<<dim3(128, 9, 2), 256, 0, stream>>>(
        Wqkvb, XbT, Y, 1152, SPX, 384, (long)SPX * 384, (long)1152 * SPX, 1.0f);
    dwconv3x3v2<<<dim3(2, 2304), 256, 0, stream>>>(Y, dw_w, QKV);

    // stage 2-3: Gram + norms, cosine softmax
    hipMemsetAsync(G, 0, 153600, stream);
    gram48<<<dim3(32, 16), 256, 0, stream>>>(QKV, G, NQ, NK);
    attn_softmax48<<<dim3(16), dim3(64), 0, stream>>>(G, NQ, NK, temp4, AAT);

    // stage 4: outcT = (A @ v)^T  (bf16, [s][c] layout)
    applyv48<<<dim3(64, 16), 256, 0, stream>>>(QKV, AAT, outcT);

    // stage 5: out = 2 * (proj_w @ outc)  (fp32 out)
    gemm_bt<0><<<dim3(128, 3, 2), 256, 0, stream>>>(
        Wprojb, outcT, out, 384, SPX, 384, (long)SPX * 384, (long)384 * SPX, 2.0f);
}

// Round 6
// 318.143 us; speedup vs baseline: 2.9312x; 1.0154x over previous
//
#include <hip/hip_runtime.h>
#include <math.h>

#define SPX 16384   // H*W = 128*128

typedef unsigned short ushort_t;
typedef __attribute__((ext_vector_type(8))) short bf16x8;
typedef __attribute__((ext_vector_type(8))) unsigned short u16x8;
typedef __attribute__((ext_vector_type(4))) float f32x4;

static __device__ __forceinline__ ushort f2bf(float f) {
    union { float f; unsigned int u; } v; v.f = f;
    unsigned int r = v.u + 0x7FFFu + ((v.u >> 16) & 1u);   // RNE
    return (ushort)(r >> 16);
}
static __device__ __forceinline__ float bf2f(ushort u) {
    union { unsigned int u; float f; } v; v.u = ((unsigned int)u) << 16;
    return v.f;
}

// ---------------------------------------------------------------------------
// Transpose + convert: X[z][C][S] fp32 -> XT[z][S][C] bf16.  64x64 tiles,
// float4 coalesced loads, u16x8 16B stores.
// ---------------------------------------------------------------------------
__global__ __launch_bounds__(256) void transpose_cvt64(
    const float* __restrict__ X, ushort* __restrict__ XT, int C, int S)
{
    __shared__ float t[64 * 68];
    const int s0 = blockIdx.x * 64, c0 = blockIdx.y * 64;
    const long zb = (long)blockIdx.z * C * S;
    const int tid = threadIdx.x;
    const int cl = tid >> 4, sw = tid & 15;
    #pragma unroll
    for (int i = 0; i < 4; ++i) {
        int c = cl + 16 * i;
        float4 v = *(const float4*)&X[zb + (long)(c0 + c) * S + s0 + sw * 4];
        *(float4*)&t[c * 68 + sw * 4] = v;
    }
    __syncthreads();
    const int sr = tid >> 2, cq = tid & 3;
    #pragma unroll
    for (int i = 0; i < 2; ++i) {
        int cg = cq + 4 * i;
        ushort o[8];
        #pragma unroll
        for (int j = 0; j < 8; ++j) o[j] = f2bf(t[(cg * 8 + j) * 68 + sr]);
        *(u16x8*)&XT[zb + (long)(s0 + sr) * C + c0 + cg * 8] = *(u16x8*)o;
    }
}

// ---------------------------------------------------------------------------
// Elementwise fp32 -> bf16 (weights)
// ---------------------------------------------------------------------------
__global__ __launch_bounds__(256) void cvt_bf16(
    const float* __restrict__ in, ushort* __restrict__ out, int n)
{
    int i = blockIdx.x * 256 + threadIdx.x;
    if (i < n) out[i] = f2bf(in[i]);
}

// ---------------------------------------------------------------------------
// bf16 MFMA GEMM (B-transposed input), 2-phase double-buffered pipeline:
//   C[z][m][n] = alpha * sum_k A[m][k] * BT[z][n][k]
// 128x128 tile, BK=32, 256 threads (4 waves 2x2), 16x16x32 MFMA.
// Pipeline: STAGE(t+1) issued BEFORE compute(t); one vmcnt-drain+barrier
// per K-step (T3-minimum recipe) so HBM/L2 latency hides under MFMA.
// Epilogue (bf16 out): repack C via LDS (pitch 130 -> <=2-way conflicts),
// store ushort8 rows (1 KB per wave-instruction).
// ---------------------------------------------------------------------------
template<int OUT_BF16>
__global__ __launch_bounds__(256) void gemm_bt2(
    const ushort* __restrict__ A, const ushort* __restrict__ BT,
    void* __restrict__ Cv, int M, int N, int K, long sB, long sC, float alpha)
{
    // pipeline: [A0|B0|A1|B1] each 128x32 ushorts (8 KB). epilogue(bf16):
    // C staged as 128 rows x pitch 130 ushorts (33280 B).
    __shared__ ushort smem[OUT_BF16 ? 16640 : 16384];
    char* smb = (char*)smem;
    const int tid = threadIdx.x;
    const int w = tid >> 6;
    const int wr = w >> 1, wc = w & 1;
    const int lane = tid & 63;
    const int grp = lane >> 4, lr = lane & 15;
    const int m0 = blockIdx.y * 128, n0 = blockIdx.x * 128;
    const char* Ab = (const char*)A;
    const char* Bb = (const char*)(BT + (long)blockIdx.z * sB);

    // per-thread staging offset: 2 x 16B chunks per 8KB tile
    const int o0 = tid * 16, o1 = (256 + tid) * 16;
    const int row0 = o0 >> 6, kb0 = o0 & 63;
    const int row1 = o1 >> 6, kb1 = o1 & 63;

    f32x4 acc[4][4] = {};
    const int NT = K >> 5;

    // prologue: stage tile 0 into buf 0
    {
        const char* ga0 = Ab + ((long)(m0 + row0) * K) * 2 + kb0;
        const char* gb0 = Bb + ((long)(n0 + row0) * K) * 2 + kb0;
        const char* ga1 = Ab + ((long)(m0 + row1) * K) * 2 + kb1;
        const char* gb1 = Bb + ((long)(n0 + row1) * K) * 2 + kb1;
        __builtin_amdgcn_global_load_lds((const __attribute__((address_space(1))) unsigned int*)ga0,
            (__attribute__((address_space(3))) unsigned int*)(smb + o0), 16, 0, 0);
        __builtin_amdgcn_global_load_lds((const __attribute__((address_space(1))) unsigned int*)gb0,
            (__attribute__((address_space(3))) unsigned int*)(smb + 8192 + o0), 16, 0, 0);
        __builtin_amdgcn_global_load_lds((const __attribute__((address_space(1))) unsigned int*)ga1,
            (__attribute__((address_space(3))) unsigned int*)(smb + o1), 16, 0, 0);
        __builtin_amdgcn_global_load_lds((const __attribute__((address_space(1))) unsigned int*)gb1,
            (__attribute__((address_space(3))) unsigned int*)(smb + 8192 + o1), 16, 0, 0);
    }
    __syncthreads();

    for (int t = 0; t < NT; ++t) {
        const int p = t & 1;
        // stage next tile into the other buffer (issue EARLY; latency hides
        // under this iteration's ds_read + MFMA)
        if (t + 1 < NT) {
            const long kc = (long)(t + 1) * 32 * 2;
            char* dst = smb + (p ^ 1) * 16384;
            const char* ga0 = Ab + ((long)(m0 + row0) * K) * 2 + kc + kb0;
            const char* gb0 = Bb + ((long)(n0 + row0) * K) * 2 + kc + kb0;
            const char* ga1 = Ab + ((long)(m0 + row1) * K) * 2 + kc + kb1;
            const char* gb1 = Bb + ((long)(n0 + row1) * K) * 2 + kc + kb1;
            __builtin_amdgcn_global_load_lds((const __attribute__((address_space(1))) unsigned int*)ga0,
                (__attribute__((address_space(3))) unsigned int*)(dst + o0), 16, 0, 0);
            __builtin_amdgcn_global_load_lds((const __attribute__((address_space(1))) unsigned int*)gb0,
                (__attribute__((address_space(3))) unsigned int*)(dst + 8192 + o0), 16, 0, 0);
            __builtin_amdgcn_global_load_lds((const __attribute__((address_space(1))) unsigned int*)ga1,
                (__attribute__((address_space(3))) unsigned int*)(dst + o1), 16, 0, 0);
            __builtin_amdgcn_global_load_lds((const __attribute__((address_space(1))) unsigned int*)gb1,
                (__attribute__((address_space(3))) unsigned int*)(dst + 8192 + o1), 16, 0, 0);
        }
        const ushort* As = smem + p * 8192;
        const ushort* Bs = As + 4096;
        bf16x8 av[4], bv[4];
        #pragma unroll
        for (int mi = 0; mi < 4; ++mi)
            av[mi] = *(const bf16x8*)&As[(wr * 64 + mi * 16 + lr) * 32 + grp * 8];
        #pragma unroll
        for (int ni = 0; ni < 4; ++ni)
            bv[ni] = *(const bf16x8*)&Bs[(wc * 64 + ni * 16 + lr) * 32 + grp * 8];
        #pragma unroll
        for (int mi = 0; mi < 4; ++mi)
            #pragma unroll
            for (int ni = 0; ni < 4; ++ni)
                acc[mi][ni] = __builtin_amdgcn_mfma_f32_16x16x32_bf16(
                    av[mi], bv[ni], acc[mi][ni], 0, 0, 0);
        // one drain+barrier per K-step: waits for the stage issued above,
        // whose latency was overlapped with the MFMA block
        __syncthreads();
    }

    const long cb = (long)blockIdx.z * sC;
    if (OUT_BF16) {
        // repack via LDS: pitch 130 ushorts keeps both phases <=2-way
        #pragma unroll
        for (int mi = 0; mi < 4; ++mi)
            #pragma unroll
            for (int ni = 0; ni < 4; ++ni) {
                const int r0 = wr * 64 + mi * 16 + grp * 4;
                const int c  = wc * 64 + ni * 16 + lr;
                #pragma unroll
                for (int j = 0; j < 4; ++j)
                    smem[(r0 + j) * 130 + c] = f2bf(acc[mi][ni][j] * alpha);
            }
        __syncthreads();
        #pragma unroll
        for (int i = 0; i < 8; ++i) {
            int ch = tid + i * 256;            // 2048 chunks = 128 rows x 16
            int r = ch >> 4, cc = ch & 15;
            u16x8 v = *(const u16x8*)&smem[r * 130 + cc * 8];
            *(u16x8*)&((ushort*)Cv)[cb + (long)(m0 + r) * N + n0 + cc * 8] = v;
        }
    } else {
        #pragma unroll
        for (int mi = 0; mi < 4; ++mi)
            #pragma unroll
            for (int ni = 0; ni < 4; ++ni) {
                const int r0 = m0 + wr * 64 + mi * 16 + grp * 4;
                const int c  = n0 + wc * 64 + ni * 16 + lr;
                #pragma unroll
                for (int j = 0; j < 4; ++j)
                    ((float*)Cv)[cb + (long)(r0 + j) * N + c] = acc[mi][ni][j] * alpha;
            }
    }
}

// ---------------------------------------------------------------------------
// Depthwise 3x3, SAME (zero pad), H=W=128, bf16 in/out, fp32 weights.
// Block = (channel, 64-row group); thread = 4x8 output tile.
// ---------------------------------------------------------------------------
__global__ __launch_bounds__(256) void dwconv3x3v2(
    const ushort* __restrict__ Y, const float* __restrict__ Wd, ushort* __restrict__ O)
{
    __shared__ ushort rows[66 * 152];   // data at cols 8..135; zero pads at 7,136
    const int ci = blockIdx.y;
    const int y0 = blockIdx.x * 64;
    const int tid = threadIdx.x;
    const ushort* __restrict__ src = Y + (long)ci * SPX;
    const float* wp = Wd + (ci % 1152) * 9;

    for (int ch = tid; ch < 1056; ch += 256) {   // 66 rows x 16 chunks
        int r = ch >> 4, xcs = ch & 15;
        int gy = y0 + r - 1;
        u16x8 v;
        if ((unsigned)gy < 128u) v = *(const u16x8*)&src[gy * 128 + xcs * 8];
        else                     v = (u16x8)0;
        *(u16x8*)&rows[r * 152 + 8 + xcs * 8] = v;
    }
    if (tid < 66) { rows[tid * 152 + 7] = 0; rows[tid * 152 + 136] = 0; }
    __syncthreads();

    const float w00 = wp[0], w01 = wp[1], w02 = wp[2];
    const float w10 = wp[3], w11 = wp[4], w12 = wp[5];
    const float w20 = wp[6], w21 = wp[7], w22 = wp[8];

    const int ry = tid >> 4, xc = tid & 15;
    float acc[4][8] = {};
    #pragma unroll
    for (int ir = 0; ir < 6; ++ir) {
        const int t = 4 * ry + ir;
        const ushort* rb = &rows[t * 152 + xc * 8];
        u16x8 c0 = *(const u16x8*)(rb);
        u16x8 c1 = *(const u16x8*)(rb + 8);
        u16x8 c2 = *(const u16x8*)(rb + 16);
        float win[10];
        win[0] = bf2f(c0[7]);
        #pragma unroll
        for (int j = 0; j < 8; ++j) win[j + 1] = bf2f(c1[j]);
        win[9] = bf2f(c2[0]);
        if (ir >= 2) {
            #pragma unroll
            for (int j = 0; j < 8; ++j)
                acc[ir - 2][j] += w20 * win[j] + w21 * win[j + 1] + w22 * win[j + 2];
        }
        if (ir >= 1 && ir <= 4) {
            #pragma unroll
            for (int j = 0; j < 8; ++j)
                acc[ir - 1][j] += w10 * win[j] + w11 * win[j + 1] + w12 * win[j + 2];
        }
        if (ir <= 3) {
            #pragma unroll
            for (int j = 0; j < 8; ++j)
                acc[ir][j] += w00 * win[j] + w01 * win[j + 1] + w02 * win[j + 2];
        }
    }
    #pragma unroll
    for (int q = 0; q < 4; ++q) {
        ushort o[8];
        #pragma unroll
        for (int j = 0; j < 8; ++j) o[j] = f2bf(acc[q][j]);
        *(u16x8*)&O[(long)ci * SPX + (y0 + 4 * ry + q) * 128 + xc * 8] = *(u16x8*)o;
    }
}

// ---------------------------------------------------------------------------
// Gram + norms per (n,head): G[c][d] = sum_s q[c][s]*k[d][s] (fp32 from bf16);
// split-K over 32 chunks of 512, atomics.
// ---------------------------------------------------------------------------
__global__ __launch_bounds__(256) void gram48(
    const ushort* __restrict__ qkv, float* __restrict__ G,
    float* __restrict__ nq, float* __restrict__ nk)
{
    __shared__ float qs[48 * 132];
    __shared__ float ks[48 * 132];
    const int g = blockIdx.y;
    const int nb = g >> 3, h = g & 7;
    const long qb = ((long)nb * 1152 + h * 48) * SPX;
    const long kb = qb + 384L * SPX;
    const int tid = threadIdx.x;
    const int cg = tid >> 4, dg = tid & 15;
    float acc[3][3] = {};
    float nacc = 0.f;
    const int nc = tid % 48, nwhich = tid / 48;
    const int sch = blockIdx.x * 512;

    for (int sc = 0; sc < 4; ++sc) {
        const int sb = sch + sc * 128;
        __syncthreads();
        #pragma unroll
        for (int i = 0; i < 6; ++i) {
            int e = (i * 256 + tid) * 4;         // 6144 elems, 4/thread
            int c = e >> 7, s = e & 127;
            ushort4 uq = *(const ushort4*)&qkv[qb + (long)c * SPX + sb + s];
            ushort4 uk = *(const ushort4*)&qkv[kb + (long)c * SPX + sb + s];
            float4 fq = { bf2f(uq.x), bf2f(uq.y), bf2f(uq.z), bf2f(uq.w) };
            float4 fk = { bf2f(uk.x), bf2f(uk.y), bf2f(uk.z), bf2f(uk.w) };
            *(float4*)&qs[c * 132 + s] = fq;
            *(float4*)&ks[c * 132 + s] = fk;
        }
        __syncthreads();
        const float4* q0 = (const float4*)&qs[(cg * 3 + 0) * 132];
        const float4* q1 = (const float4*)&qs[(cg * 3 + 1) * 132];
        const float4* q2 = (const float4*)&qs[(cg * 3 + 2) * 132];
        const float4* k0 = (const float4*)&ks[(dg * 3 + 0) * 132];
        const float4* k1 = (const float4*)&ks[(dg * 3 + 1) * 132];
        const float4* k2 = (const float4*)&ks[(dg * 3 + 2) * 132];
        #pragma unroll 8
        for (int s4 = 0; s4 < 32; ++s4) {
            float4 qv[3] = { q0[s4], q1[s4], q2[s4] };
            float4 kv[3] = { k0[s4], k1[s4], k2[s4] };
            #pragma unroll
            for (int i = 0; i < 3; ++i)
                #pragma unroll
                for (int j = 0; j < 3; ++j)
                    acc[i][j] += qv[i].x * kv[j].x + qv[i].y * kv[j].y
                               + qv[i].z * kv[j].z + qv[i].w * kv[j].w;
        }
        if (tid < 96) {
            const float4* nr4 = (const float4*)((nwhich ? ks : qs) + nc * 132);
            #pragma unroll 8
            for (int s4 = 0; s4 < 32; ++s4) {
                float4 v = nr4[s4];
                nacc += v.x * v.x + v.y * v.y + v.z * v.z + v.w * v.w;
            }
        }
    }
    #pragma unroll
    for (int i = 0; i < 3; ++i)
        #pragma unroll
        for (int j = 0; j < 3; ++j)
            atomicAdd(&G[g * 2304 + (cg * 3 + i) * 48 + (dg * 3 + j)], acc[i][j]);
    if (tid < 96) atomicAdd((nwhich ? nk : nq) + g * 48 + nc, nacc);
}

// ---------------------------------------------------------------------------
// A[c][d] = softmax_d( G[c][d] / (max(|q_c|,eps)*max(|k_d|,eps)) * temp4[h] )
// ---------------------------------------------------------------------------
__global__ void attn_softmax48(const float* __restrict__ G, const float* __restrict__ nq,
                               const float* __restrict__ nk, const float* __restrict__ temp4,
                               float* __restrict__ A)
{
    const int g = blockIdx.x;
    const int c = threadIdx.x;
    if (c >= 48) return;
    const int h = g & 7;
    const float t = temp4[h];
    const float rq = 1.f / fmaxf(sqrtf(nq[g * 48 + c]), 1e-12f);
    float row[48];
    float mx = -1e30f;
    #pragma unroll
    for (int d = 0; d < 48; ++d) {
        float rk = 1.f / fmaxf(sqrtf(nk[g * 48 + d]), 1e-12f);
        float v = G[g * 2304 + c * 48 + d] * rq * rk * t;
        row[d] = v;
        mx = fmaxf(mx, v);
    }
    float sum = 0.f;
    #pragma unroll
    for (int d = 0; d < 48; ++d) { float e = expf(row[d] - mx); row[d] = e; sum += e; }
    const float inv = 1.f / sum;
    #pragma unroll
    for (int d = 0; d < 48; ++d) A[g * 2304 + c * 48 + d] = row[d] * inv;
}

// ---------------------------------------------------------------------------
// outT[nb][s][h*48+c] = sum_d A[c][d] * v[d][s]  (bf16 out, transposed layout)
// ---------------------------------------------------------------------------
__global__ __launch_bounds__(256) void applyv48(
    const ushort* __restrict__ qkv, const float* __restrict__ A, ushort* __restrict__ outT)
{
    __shared__ float AT[48 * 52];     // AT[d][c]
    __shared__ float vs[48 * 256];
    const int g = blockIdx.y, tid = threadIdx.x;
    const int nb = g >> 3, h = g & 7;
    const long vb = ((long)nb * 1152 + 768 + h * 48) * SPX;
    const int s0 = blockIdx.x * 256;
    #pragma unroll
    for (int i = 0; i < 9; ++i) {
        int idx = tid + i * 256;                 // 2304
        int c = idx / 48, d = idx % 48;
        AT[d * 52 + c] = A[g * 2304 + idx];
    }
    #pragma unroll
    for (int i = 0; i < 12; ++i) {
        int e = (i * 256 + tid) * 4;             // 12288 elems, 4/thread
        int d = e >> 8, s = e & 255;
        ushort4 uv = *(const ushort4*)&qkv[vb + (long)d * SPX + s0 + s];
        float4 fv = { bf2f(uv.x), bf2f(uv.y), bf2f(uv.z), bf2f(uv.w) };
        *(float4*)&vs[d * 256 + s] = fv;
    }
    __syncthreads();
    const long ob = (long)nb * SPX * 384 + (long)(s0 + tid) * 384 + h * 48;
    for (int cg = 0; cg < 12; ++cg) {
        float a0 = 0.f, a1 = 0.f, a2 = 0.f, a3 = 0.f;
        #pragma unroll
        for (int d = 0; d < 48; ++d) {
            float vd = vs[d * 256 + tid];
            float4 av = *(const float4*)&AT[d * 52 + cg * 4];
            a0 = fmaf(av.x, vd, a0);
            a1 = fmaf(av.y, vd, a1);
            a2 = fmaf(av.z, vd, a2);
            a3 = fmaf(av.w, vd, a3);
        }
        ushort4 o = { f2bf(a0), f2bf(a1), f2bf(a2), f2bf(a3) };
        *(ushort4*)&outT[ob + cg * 4] = o;
    }
}

// ---------------------------------------------------------------------------
// Workspace (bytes):
//   XbT/outcT : [0, 25165824)            2*16384*384 bf16 (aliased; stage-disjoint)
//   Wqkvb     : [25165824, +884736)
//   Wprojb    : [26050560, +294912)
//   Y         : [26345472, +75497472)    2*1152*16384 bf16
//   QKV       : [101842944, +75497472)
//   G/NQ/NK/AAT: [177340416, +301056)
// total ~169.4 MiB
// ---------------------------------------------------------------------------
extern "C" void kernel_launch(void* const* d_in, const int* in_sizes, int n_in,
                              void* d_out, int out_size, void* d_ws, size_t ws_size,
                              hipStream_t stream)
{
    const float* x      = (const float*)d_in[0];
    const float* qkv_w  = (const float*)d_in[2];
    const float* dw_w   = (const float*)d_in[3];
    const float* proj_w = (const float*)d_in[4];
    const float* temp4  = (const float*)d_in[7];
    char* wsb = (char*)d_ws;
    float* out = (float*)d_out;

    ushort* XbT    = (ushort*)(wsb);
    ushort* Wqkvb  = (ushort*)(wsb + 25165824L);
    ushort* Wprojb = (ushort*)(wsb + 26050560L);
    ushort* Y      = (ushort*)(wsb + 26345472L);
    ushort* QKV    = (ushort*)(wsb + 101842944L);
    float*  G      = (float*)(wsb + 177340416L);
    float*  NQ     = G + 36864;
    float*  NK     = NQ + 768;
    float*  AAT    = NK + 768;
    ushort* outcT  = XbT;   // alias: XbT dead after qkv GEMM

    // stage 0: convert inputs
    transpose_cvt64<<<dim3(256, 6, 2), 256, 0, stream>>>(x, XbT, 384, SPX);
    cvt_bf16<<<dim3(1728), 256, 0, stream>>>(qkv_w, Wqkvb, 1152 * 384);
    cvt_bf16<<<dim3(576), 256, 0, stream>>>(proj_w, Wprojb, 384 * 384);

    // stage 1: Y = qkv_w @ x  (bf16 MFMA, 2-phase), then depthwise 3x3 -> QKV
    gemm_bt2<1><<<dim3(128, 9, 2), 256, 0, stream>>>(
        Wqkvb, XbT, Y, 1152, SPX, 384, (long)SPX * 384, (long)1152 * SPX, 1.0f);
    dwconv3x3v2<<<dim3(2, 2304), 256, 0, stream>>>(Y, dw_w, QKV);

    // stage 2-3: Gram + norms, cosine softmax
    hipMemsetAsync(G, 0, 153600, stream);
    gram48<<<dim3(32, 16), 256, 0, stream>>>(QKV, G, NQ, NK);
    attn_softmax48<<<dim3(16), dim3(64), 0, stream>>>(G, NQ, NK, temp4, AAT);

    // stage 4: outcT = (A @ v)^T  (bf16, [s][c] layout)
    applyv48<<<dim3(64, 16), 256, 0, stream>>>(QKV, AAT, outcT);

    // stage 5: out = 2 * (proj_w @ outc)  (fp32 out)
    gemm_bt2<0><<<dim3(128, 3, 2), 256, 0, stream>>>(
        Wprojb, outcT, out, 384, SPX, 384, (long)SPX * 384, (long)384 * SPX, 2.0f);
}